// Round 15
// baseline (282.278 us; speedup 1.0000x reference)
//
#include <hip/hip_runtime.h>
#include <cstdint>
#include <cstddef>

// Problem constants
#define B_  8192
#define T_  96
#define K_  32
#define H_  768
#define NK_ (T_ * K_)   // 3072

typedef __attribute__((ext_vector_type(8))) _Float16 f16x8;
typedef __attribute__((ext_vector_type(4))) float    f32x4;

#define SCALE_UP   4096.0f               // 2^12 on A and W each
#define SCALE_DOWN (1.0f / 16777216.0f)  // 2^-24

__device__ __forceinline__ void load_lds16(const void* g, void* l) {
    __builtin_amdgcn_global_load_lds(
        (const __attribute__((address_space(1))) unsigned int*)g,
        (__attribute__((address_space(3))) unsigned int*)l,
        16, 0, 0);
}

// ---------------------------------------------------------------------------
// Fused prepass (R14-proven): splits A and W (*4096) into fp16 hi/lo tiles.
// ---------------------------------------------------------------------------
__global__ __launch_bounds__(256) void split_fused_kernel(
    const float* __restrict__ A, const float* __restrict__ W,
    _Float16* __restrict__ Ath, _Float16* __restrict__ Atl,
    _Float16* __restrict__ Wth, _Float16* __restrict__ Wtl)
{
    int g = blockIdx.x * 256 + threadIdx.x;
    if (g < B_ * 96) {
        const int row = g / 96;
        const int o   = g - row * 96;
        const int ks  = o >> 2, qq = o & 3;
        const int r   = row & 127, rb = row >> 7;
        const size_t dst = (size_t)(rb * 24 + ks) * 4096 + r * 32 + ((qq ^ ((r >> 1) & 3)) << 3);

        f32x4 v0 = *(const f32x4*)(A + (size_t)row * H_ + o * 8);
        f32x4 v1 = *(const f32x4*)(A + (size_t)row * H_ + o * 8 + 4);
        f16x8 hi, lo;
#pragma unroll
        for (int e = 0; e < 8; e++) {
            float x = ((e < 4) ? v0[e] : v1[e - 4]) * SCALE_UP;
            _Float16 h = (_Float16)x;
            hi[e] = h;
            lo[e] = (_Float16)(x - (float)h);
        }
        *(f16x8*)&Ath[dst] = hi;
        *(f16x8*)&Atl[dst] = lo;
    } else {
        g -= B_ * 96;
        const int ko  = g / NK_;
        const int col = g - ko * NK_;
        const int k0  = ko * 8;
        const int cb  = col >> 7, n = col & 127;
        const int ks  = k0 >> 5, qq = (k0 & 31) >> 3;
        const size_t dst = (size_t)(cb * 24 + ks) * 4096 + n * 32 + ((qq ^ ((n >> 1) & 3)) << 3);

        f16x8 hi, lo;
#pragma unroll
        for (int j = 0; j < 8; j++) {
            float x = W[(size_t)(k0 + j) * NK_ + col] * SCALE_UP;
            _Float16 h = (_Float16)x;
            hi[j] = h;
            lo[j] = (_Float16)(x - (float)h);
        }
        *(f16x8*)&Wth[dst] = hi;
        *(f16x8*)&Wtl[dst] = lo;
    }
}

// ---------------------------------------------------------------------------
// GEMM v2: 3-buffer LDS, depth-2 prefetch, counted vmcnt across raw barrier
// (T3/T4 pattern). One barrier per K-step; vmcnt(8) leaves next tile's loads
// in flight. Same MFMA order as the proven kernel (numerics identical).
// ---------------------------------------------------------------------------
__global__ __launch_bounds__(256, 1) void gemm_mfma_sigmoid_kernel(
    const _Float16* __restrict__ Ath, const _Float16* __restrict__ Atl,
    const _Float16* __restrict__ Wth, const _Float16* __restrict__ Wtl,
    const float* __restrict__ bias, float* __restrict__ em)
{
    __shared__ _Float16 lds[3][4][4096];   // 96 KB -> 1 block/CU

    const int tid  = threadIdx.x;
    const int bid  = blockIdx.x;
    const int wgid = (bid & 7) * 192 + (bid >> 3);   // bijective XCD swizzle
    const int cb   = wgid % 24;
    const int rb   = wgid / 24;
    const int lane = tid & 63;
    const int w    = tid >> 6;
    const int wr   = w >> 1, wc = w & 1;
    const int fr   = lane & 15;
    const int kg   = lane >> 4;

    const _Float16* srcs[4] = {
        Ath + (size_t)(rb * 24) * 4096, Atl + (size_t)(rb * 24) * 4096,
        Wth + (size_t)(cb * 24) * 4096, Wtl + (size_t)(cb * 24) * 4096 };

    auto stage = [&](int ks, int bb) {
#pragma unroll
        for (int m = 0; m < 4; m++) {
            const _Float16* s = srcs[m] + (size_t)ks * 4096 + w * 1024 + lane * 8;
            _Float16* d = &lds[bb][m][w * 1024];
            load_lds16(s, d);
            load_lds16(s + 512, d + 512);
        }
    };

    f32x4 acc[4][4];
#pragma unroll
    for (int i = 0; i < 4; i++)
#pragma unroll
        for (int j = 0; j < 4; j++) acc[i][j] = (f32x4)0.0f;

    stage(0, 0);          // 8 loads (oldest)
    stage(1, 1);          // 8 loads

    for (int ks = 0; ks < 24; ks++) {
        // Wait for tile-ks's loads only; tile-(ks+1)'s 8 stay in flight.
        if (ks < 23) asm volatile("s_waitcnt vmcnt(8)" ::: "memory");
        else         asm volatile("s_waitcnt vmcnt(0)" ::: "memory");
        __builtin_amdgcn_s_barrier();           // raw barrier: no vmcnt drain
        __builtin_amdgcn_sched_barrier(0);      // fence: nothing moves across

        if (ks + 2 < 24) stage(ks + 2, (ks + 2) % 3);

        const int cur = ks % 3;
        f16x8 fah[4], fal[4], fbh[4], fbl[4];
#pragma unroll
        for (int mi = 0; mi < 4; mi++) {
            const int r   = wr * 64 + mi * 16 + fr;
            const int idx = r * 32 + ((kg ^ ((r >> 1) & 3)) << 3);
            fah[mi] = *(const f16x8*)&lds[cur][0][idx];
            fal[mi] = *(const f16x8*)&lds[cur][1][idx];
        }
#pragma unroll
        for (int ni = 0; ni < 4; ni++) {
            const int r   = wc * 64 + ni * 16 + fr;
            const int idx = r * 32 + ((kg ^ ((r >> 1) & 3)) << 3);
            fbh[ni] = *(const f16x8*)&lds[cur][2][idx];
            fbl[ni] = *(const f16x8*)&lds[cur][3][idx];
        }
#pragma unroll
        for (int mi = 0; mi < 4; mi++)
#pragma unroll
            for (int ni = 0; ni < 4; ni++) {
                acc[mi][ni] = __builtin_amdgcn_mfma_f32_16x16x32_f16(fah[mi], fbh[ni], acc[mi][ni], 0, 0, 0);
                acc[mi][ni] = __builtin_amdgcn_mfma_f32_16x16x32_f16(fah[mi], fbl[ni], acc[mi][ni], 0, 0, 0);
                acc[mi][ni] = __builtin_amdgcn_mfma_f32_16x16x32_f16(fal[mi], fbh[ni], acc[mi][ni], 0, 0, 0);
            }
    }

    const int er = rb * 128 + wr * 64 + (lane >> 4) * 4;
    const int ec = cb * 128 + wc * 64 + fr;
#pragma unroll
    for (int ni = 0; ni < 4; ni++) {
        const int   gc = ec + ni * 16;
        const float bv = bias[gc];
#pragma unroll
        for (int mi = 0; mi < 4; mi++)
#pragma unroll
            for (int r = 0; r < 4; r++) {
                const int gr = er + mi * 16 + r;
                float x = acc[mi][ni][r] * SCALE_DOWN + bv;
                em[(size_t)gr * NK_ + gc] = 1.0f / (1.0f + __expf(-x));
            }
    }
}

// ---------------------------------------------------------------------------
// CRF: R11 kernel VERBATIM (measured best: 131 us, absmax 0).
// ---------------------------------------------------------------------------

#define VSTEP(T_, SH_, WI_)                                               \
  {                                                                       \
    const float cem = na; na = emb[((T_) + 1) * K_];                      \
    vxs[k] = va;                                                          \
    __builtin_amdgcn_wave_barrier();                                      \
    float bva = -1e30f; int bia = 0;                                      \
    _Pragma("unroll")                                                     \
    for (int j = 0; j < 8; j++) {                                         \
      f32x4 vq = *(const f32x4*)&vxs[4 * j];                              \
      float s0 = vq[0] + tca[4 * j];                                      \
      float s1 = vq[1] + tca[4 * j + 1];                                  \
      float s2 = vq[2] + tca[4 * j + 2];                                  \
      float s3 = vq[3] + tca[4 * j + 3];                                  \
      float w0 = (s1 > s0) ? s1 : s0;                                     \
      int   i0 = (s1 > s0) ? (4 * j + 1) : (4 * j);                       \
      float w1 = (s3 > s2) ? s3 : s2;                                     \
      int   i1 = (s3 > s2) ? (4 * j + 3) : (4 * j + 2);                   \
      if (w1 > w0) { w0 = w1; i0 = i1; }                                  \
      if (w0 > bva) { bva = w0; bia = i0; }                               \
    }                                                                     \
    va = bva + cem;                                                       \
    bpw |= (unsigned int)bia << (5 * (SH_));                              \
    if ((SH_) == 5) { bps[k * 17 + (WI_)] = bpw; bpw = 0; }               \
    __builtin_amdgcn_wave_barrier();                                      \
  }

__global__ __launch_bounds__(256, 4) void crf_roles_kernel(
    const float* __restrict__ em,       // [B_, NK_]
    const int* __restrict__ target,     // [B_, T_]
    const float* __restrict__ trans,    // [K_, K_]
    float* __restrict__ out_tags,       // [B_, T_]
    float* __restrict__ ll)             // [B_]
{
    __shared__ float trans_s[K_ * K_];        // 4 KB
    __shared__ float Eex[4][36];              // fwd exchange
    __shared__ float vex[4][36];              // vit exchange
    __shared__ unsigned int bp5[4][545];      // 8.7 KB (col stride 17, coprime 32)
    __shared__ unsigned char tgt_s[4][T_];    // 384 B

    const int tid  = threadIdx.x;
    const int w    = tid >> 6;
    const int lane = tid & 63;
    const int half = lane >> 5;
    const int k    = lane & 31;
    const bool isFwd = (w < 2);
    const int s    = (((isFwd ? w : w - 2) << 1) | half);   // seq-in-block 0..3
    const int b    = blockIdx.x * 4 + s;

    for (int i = tid; i < K_ * K_; i += 256) trans_s[i] = trans[i];
    __syncthreads();

    const float* emb = em + (size_t)b * NK_ + k;

    if (isFwd) {
        // ================== FORWARD (ll) ==================
        float Ea2[K_];
#pragma unroll
        for (int p = 0; p < K_; p++) Ea2[p] = __expf(trans_s[p * K_ + k]);

        const int t0 = target[b * T_ + k];
        const int t1 = target[b * T_ + 32 + k];
        const int t2 = target[b * T_ + 64 + k];
        tgt_s[s][k]      = (unsigned char)t0;
        tgt_s[s][k + 32] = (unsigned char)t1;
        tgt_s[s][k + 64] = (unsigned char)t2;
        __builtin_amdgcn_wave_barrier();
        const float* emrow = em + (size_t)b * NK_;
        float gold = emrow[k * K_ + t0] + emrow[(k + 32) * K_ + t1] + emrow[(k + 64) * K_ + t2];
        if (k > 0) gold += trans_s[(int)tgt_s[s][k - 1] * K_ + t0];
        gold += trans_s[(int)tgt_s[s][k + 31] * K_ + t1];
        gold += trans_s[(int)tgt_s[s][k + 63] * K_ + t2];

        float Ea = __expf(emb[0]);
        int   expo_sum = 0;
        float na = emb[K_];                   // prefetch t=1
        float* exs = &Eex[s][0];

        for (int t = 1; t <= 95; ++t) {
            const float cem = na;
            na = emb[(t + 1) * K_];           // t=95 reads split region: allocated, unused
            exs[k] = Ea;
            __builtin_amdgcn_wave_barrier();
            float fa = 0.0f;
#pragma unroll
            for (int j = 0; j < 8; j++) {
                f32x4 q = *(const f32x4*)&exs[4 * j];
                fa = fmaf(q[0], Ea2[4 * j],     fa);
                fa = fmaf(q[1], Ea2[4 * j + 1], fa);
                fa = fmaf(q[2], Ea2[4 * j + 2], fa);
                fa = fmaf(q[3], Ea2[4 * j + 3], fa);
            }
            Ea = fa * __expf(cem - 4.0f);
            __builtin_amdgcn_wave_barrier();

            if ((t % 12) == 0) {              // exact pow2 renorm
                float m = Ea;
#pragma unroll
                for (int d = 16; d >= 1; d >>= 1) m = fmaxf(m, __shfl_xor(m, d));
                const unsigned int ebits = (__float_as_uint(m) >> 23) & 255u;
                const float sc = __uint_as_float((254u - ebits) << 23);
                Ea *= sc;
                expo_sum += (int)ebits - 127;
            }
        }

        float S = Ea;
#pragma unroll
        for (int d = 16; d >= 1; d >>= 1) S += __shfl_xor(S, d);
        const float logZ = __logf(S) + 380.0f + (float)expo_sum * 0.69314718055994531f;

        float gs = gold;
#pragma unroll
        for (int d = 16; d >= 1; d >>= 1) gs += __shfl_xor(gs, d);

        if (k == 0) ll[b] = gs - logZ;

    } else {
        // ================== VITERBI (tags) ==================
        float tca[K_];
#pragma unroll
        for (int p = 0; p < K_; p++) tca[p] = trans_s[p * K_ + k];

        float va = emb[0];
        float na = emb[K_];                   // prefetch t=1
        unsigned int bpw = 0;
        float* vxs = &vex[s][0];
        unsigned int* bps = &bp5[s][0];

        for (int it = 0; it < 7; ++it) {      // t = 1..84
            const int tb = it * 12 + 1;
            const int wi = it * 2;
            VSTEP(tb + 0, 0, wi)  VSTEP(tb + 1, 1, wi)  VSTEP(tb + 2, 2, wi)
            VSTEP(tb + 3, 3, wi)  VSTEP(tb + 4, 4, wi)  VSTEP(tb + 5, 5, wi)
            VSTEP(tb + 6, 0, wi + 1)  VSTEP(tb + 7, 1, wi + 1)  VSTEP(tb + 8, 2, wi + 1)
            VSTEP(tb + 9, 3, wi + 1)  VSTEP(tb + 10, 4, wi + 1) VSTEP(tb + 11, 5, wi + 1)
        }
        VSTEP(85, 0, 14) VSTEP(86, 1, 14) VSTEP(87, 2, 14)
        VSTEP(88, 3, 14) VSTEP(89, 4, 14) VSTEP(90, 5, 14)
        VSTEP(91, 0, 15) VSTEP(92, 1, 15) VSTEP(93, 2, 15)
        VSTEP(94, 3, 15) VSTEP(95, 4, 15)
        bps[k * 17 + 15] = bpw;               // partial word 15 (slots 0..4)
        __builtin_amdgcn_wave_barrier();

        // final argmax over 32 lanes (first-index tie-break)
        float bv = va; int bi = k;
#pragma unroll
        for (int d = 16; d >= 1; d >>= 1) {
            float ov = __shfl_xor(bv, d);
            int   oi = __shfl_xor(bi, d);
            if (ov > bv || (ov == bv && oi < bi)) { bv = ov; bi = oi; }
        }

        if (k == 0) {
            float* ot = out_tags + (size_t)b * T_;
            int tag = bi;
            ot[T_ - 1] = (float)tag;
            for (int t = T_ - 2; t >= 0; t--) {
                unsigned int wd = bps[tag * 17 + t / 6];
                tag = (int)((wd >> (5 * (t % 6))) & 31u);
                ot[t] = (float)tag;
            }
        }
    }
}

// ---------------------------------------------------------------------------
extern "C" void kernel_launch(void* const* d_in, const int* in_sizes, int n_in,
                              void* d_out, int out_size, void* d_ws, size_t ws_size,
                              hipStream_t stream)
{
    const float* hidden = (const float*)d_in[0];
    const int*   target = (const int*)d_in[1];
    const float* W      = (const float*)d_in[2];
    const float* bias   = (const float*)d_in[3];
    const float* trans  = (const float*)d_in[4];

    float* out      = (float*)d_out;
    float* out_tags = out;                    // B_*T_ tags (as f32)
    float* out_ll   = out + (size_t)B_ * T_;  // B_ log-likelihoods

    char* ws = (char*)d_ws;
    const size_t emB = (size_t)B_ * NK_ * 4;   // 100.66 MB
    const size_t ahB = (size_t)B_ * H_ * 2;    // 12.58 MB
    const size_t whB = (size_t)H_ * NK_ * 2;   // 4.72 MB

    float*    em  = (float*)ws;
    _Float16* Ath = (_Float16*)(ws + emB);
    _Float16* Atl = (_Float16*)(ws + emB + ahB);
    _Float16* Wth = (_Float16*)(ws + emB + 2 * ahB);
    _Float16* Wtl = (_Float16*)(ws + emB + 2 * ahB + whB);

    split_fused_kernel<<<(B_ * 96 + NK_ * 96) / 256, 256, 0, stream>>>(
        hidden, W, Ath, Atl, Wth, Wtl);

    gemm_mfma_sigmoid_kernel<<<1536, 256, 0, stream>>>(Ath, Atl, Wth, Wtl, bias, em);

    crf_roles_kernel<<<B_ / 4, 256, 0, stream>>>(em, target, trans, out_tags, out_ll);
}

// Round 16
// 248.533 us; speedup vs baseline: 1.1358x; 1.1358x over previous
//
#include <hip/hip_runtime.h>
#include <cstdint>
#include <cstddef>

// Problem constants
#define B_  8192
#define T_  96
#define K_  32
#define H_  768
#define NK_ (T_ * K_)   // 3072

typedef __attribute__((ext_vector_type(8))) _Float16 f16x8;
typedef __attribute__((ext_vector_type(4))) float    f32x4;

#define SCALE_UP   4096.0f               // 2^12 on A and W each
#define SCALE_DOWN (1.0f / 16777216.0f)  // 2^-24

__device__ __forceinline__ void load_lds16(const void* g, void* l) {
    __builtin_amdgcn_global_load_lds(
        (const __attribute__((address_space(1))) unsigned int*)g,
        (__attribute__((address_space(3))) unsigned int*)l,
        16, 0, 0);
}

// ---------------------------------------------------------------------------
// Fused prepass (R14-measured): splits A and W (*4096) into fp16 hi/lo tiles.
// ---------------------------------------------------------------------------
__global__ __launch_bounds__(256) void split_fused_kernel(
    const float* __restrict__ A, const float* __restrict__ W,
    _Float16* __restrict__ Ath, _Float16* __restrict__ Atl,
    _Float16* __restrict__ Wth, _Float16* __restrict__ Wtl)
{
    int g = blockIdx.x * 256 + threadIdx.x;
    if (g < B_ * 96) {
        const int row = g / 96;
        const int o   = g - row * 96;
        const int ks  = o >> 2, qq = o & 3;
        const int r   = row & 127, rb = row >> 7;
        const size_t dst = (size_t)(rb * 24 + ks) * 4096 + r * 32 + ((qq ^ ((r >> 1) & 3)) << 3);

        f32x4 v0 = *(const f32x4*)(A + (size_t)row * H_ + o * 8);
        f32x4 v1 = *(const f32x4*)(A + (size_t)row * H_ + o * 8 + 4);
        f16x8 hi, lo;
#pragma unroll
        for (int e = 0; e < 8; e++) {
            float x = ((e < 4) ? v0[e] : v1[e - 4]) * SCALE_UP;
            _Float16 h = (_Float16)x;
            hi[e] = h;
            lo[e] = (_Float16)(x - (float)h);
        }
        *(f16x8*)&Ath[dst] = hi;
        *(f16x8*)&Atl[dst] = lo;
    } else {
        g -= B_ * 96;
        const int ko  = g / NK_;
        const int col = g - ko * NK_;
        const int k0  = ko * 8;
        const int cb  = col >> 7, n = col & 127;
        const int ks  = k0 >> 5, qq = (k0 & 31) >> 3;
        const size_t dst = (size_t)(cb * 24 + ks) * 4096 + n * 32 + ((qq ^ ((n >> 1) & 3)) << 3);

        f16x8 hi, lo;
#pragma unroll
        for (int j = 0; j < 8; j++) {
            float x = W[(size_t)(k0 + j) * NK_ + col] * SCALE_UP;
            _Float16 h = (_Float16)x;
            hi[j] = h;
            lo[j] = (_Float16)(x - (float)h);
        }
        *(f16x8*)&Wth[dst] = hi;
        *(f16x8*)&Wtl[dst] = lo;
    }
}

// ---------------------------------------------------------------------------
// GEMM: R10-measured best (107.5 us). 128x128 tile, BK=32, 2-buffer LDS
// (64 KB -> 2 blocks/CU), depth-1 prefetch, bijective XCD swizzle.
// ---------------------------------------------------------------------------
__global__ __launch_bounds__(256, 2) void gemm_mfma_sigmoid_kernel(
    const _Float16* __restrict__ Ath, const _Float16* __restrict__ Atl,
    const _Float16* __restrict__ Wth, const _Float16* __restrict__ Wtl,
    const float* __restrict__ bias, float* __restrict__ em)
{
    __shared__ _Float16 lds[2][4][4096];

    const int tid  = threadIdx.x;
    const int bid  = blockIdx.x;
    const int wgid = (bid & 7) * 192 + (bid >> 3);   // bijective XCD swizzle
    const int cb   = wgid % 24;
    const int rb   = wgid / 24;
    const int lane = tid & 63;
    const int w    = tid >> 6;
    const int wr   = w >> 1, wc = w & 1;
    const int fr   = lane & 15;
    const int kg   = lane >> 4;

    const _Float16* srcs[4] = {
        Ath + (size_t)(rb * 24) * 4096, Atl + (size_t)(rb * 24) * 4096,
        Wth + (size_t)(cb * 24) * 4096, Wtl + (size_t)(cb * 24) * 4096 };

    auto stage = [&](int ks, int bb) {
#pragma unroll
        for (int m = 0; m < 4; m++) {
            const _Float16* s = srcs[m] + (size_t)ks * 4096 + w * 1024 + lane * 8;
            _Float16* d = &lds[bb][m][w * 1024];
            load_lds16(s, d);
            load_lds16(s + 512, d + 512);
        }
    };

    f32x4 acc[4][4];
#pragma unroll
    for (int i = 0; i < 4; i++)
#pragma unroll
        for (int j = 0; j < 4; j++) acc[i][j] = (f32x4)0.0f;

    int cur = 0;
    stage(0, 0);

    for (int ks = 0; ks < 24; ks++) {
        __syncthreads();
        if (ks + 1 < 24) stage(ks + 1, cur ^ 1);

        f16x8 fah[4], fal[4], fbh[4], fbl[4];
#pragma unroll
        for (int mi = 0; mi < 4; mi++) {
            const int r   = wr * 64 + mi * 16 + fr;
            const int idx = r * 32 + ((kg ^ ((r >> 1) & 3)) << 3);
            fah[mi] = *(const f16x8*)&lds[cur][0][idx];
            fal[mi] = *(const f16x8*)&lds[cur][1][idx];
        }
#pragma unroll
        for (int ni = 0; ni < 4; ni++) {
            const int r   = wc * 64 + ni * 16 + fr;
            const int idx = r * 32 + ((kg ^ ((r >> 1) & 3)) << 3);
            fbh[ni] = *(const f16x8*)&lds[cur][2][idx];
            fbl[ni] = *(const f16x8*)&lds[cur][3][idx];
        }
#pragma unroll
        for (int mi = 0; mi < 4; mi++)
#pragma unroll
            for (int ni = 0; ni < 4; ni++) {
                acc[mi][ni] = __builtin_amdgcn_mfma_f32_16x16x32_f16(fah[mi], fbh[ni], acc[mi][ni], 0, 0, 0);
                acc[mi][ni] = __builtin_amdgcn_mfma_f32_16x16x32_f16(fah[mi], fbl[ni], acc[mi][ni], 0, 0, 0);
                acc[mi][ni] = __builtin_amdgcn_mfma_f32_16x16x32_f16(fal[mi], fbh[ni], acc[mi][ni], 0, 0, 0);
            }
        cur ^= 1;
    }

    const int er = rb * 128 + wr * 64 + (lane >> 4) * 4;
    const int ec = cb * 128 + wc * 64 + fr;
#pragma unroll
    for (int ni = 0; ni < 4; ni++) {
        const int   gc = ec + ni * 16;
        const float bv = bias[gc];
#pragma unroll
        for (int mi = 0; mi < 4; mi++)
#pragma unroll
            for (int r = 0; r < 4; r++) {
                const int gr = er + mi * 16 + r;
                float x = acc[mi][ni][r] * SCALE_DOWN + bv;
                em[(size_t)gr * NK_ + gc] = 1.0f / (1.0f + __expf(-x));
            }
    }
}

// ---------------------------------------------------------------------------
// CRF: R11-measured best (131 us, VGPR 52, absmax 0) — VERBATIM.
// Role-split block: 4 seqs/block, 32 lanes/seq.
//   waves 0-1: forward (exp-space, 32 reg consts exp(T[:,k])) + gold + ll
//   waves 2-3: Viterbi (32 reg consts T[:,k]) + bp5 + lane-0 backtrace
// ---------------------------------------------------------------------------

#define VSTEP(T_, SH_, WI_)                                               \
  {                                                                       \
    const float cem = na; na = emb[((T_) + 1) * K_];                      \
    vxs[k] = va;                                                          \
    __builtin_amdgcn_wave_barrier();                                      \
    float bva = -1e30f; int bia = 0;                                      \
    _Pragma("unroll")                                                     \
    for (int j = 0; j < 8; j++) {                                         \
      f32x4 vq = *(const f32x4*)&vxs[4 * j];                              \
      float s0 = vq[0] + tca[4 * j];                                      \
      float s1 = vq[1] + tca[4 * j + 1];                                  \
      float s2 = vq[2] + tca[4 * j + 2];                                  \
      float s3 = vq[3] + tca[4 * j + 3];                                  \
      float w0 = (s1 > s0) ? s1 : s0;                                     \
      int   i0 = (s1 > s0) ? (4 * j + 1) : (4 * j);                       \
      float w1 = (s3 > s2) ? s3 : s2;                                     \
      int   i1 = (s3 > s2) ? (4 * j + 3) : (4 * j + 2);                   \
      if (w1 > w0) { w0 = w1; i0 = i1; }                                  \
      if (w0 > bva) { bva = w0; bia = i0; }                               \
    }                                                                     \
    va = bva + cem;                                                       \
    bpw |= (unsigned int)bia << (5 * (SH_));                              \
    if ((SH_) == 5) { bps[k * 17 + (WI_)] = bpw; bpw = 0; }               \
    __builtin_amdgcn_wave_barrier();                                      \
  }

__global__ __launch_bounds__(256, 4) void crf_roles_kernel(
    const float* __restrict__ em,       // [B_, NK_]
    const int* __restrict__ target,     // [B_, T_]
    const float* __restrict__ trans,    // [K_, K_]
    float* __restrict__ out_tags,       // [B_, T_]
    float* __restrict__ ll)             // [B_]
{
    __shared__ float trans_s[K_ * K_];        // 4 KB
    __shared__ float Eex[4][36];              // fwd exchange
    __shared__ float vex[4][36];              // vit exchange
    __shared__ unsigned int bp5[4][545];      // 8.7 KB (col stride 17, coprime 32)
    __shared__ unsigned char tgt_s[4][T_];    // 384 B

    const int tid  = threadIdx.x;
    const int w    = tid >> 6;
    const int lane = tid & 63;
    const int half = lane >> 5;
    const int k    = lane & 31;
    const bool isFwd = (w < 2);
    const int s    = (((isFwd ? w : w - 2) << 1) | half);   // seq-in-block 0..3
    const int b    = blockIdx.x * 4 + s;

    for (int i = tid; i < K_ * K_; i += 256) trans_s[i] = trans[i];
    __syncthreads();

    const float* emb = em + (size_t)b * NK_ + k;

    if (isFwd) {
        // ================== FORWARD (ll) ==================
        float Ea2[K_];
#pragma unroll
        for (int p = 0; p < K_; p++) Ea2[p] = __expf(trans_s[p * K_ + k]);

        const int t0 = target[b * T_ + k];
        const int t1 = target[b * T_ + 32 + k];
        const int t2 = target[b * T_ + 64 + k];
        tgt_s[s][k]      = (unsigned char)t0;
        tgt_s[s][k + 32] = (unsigned char)t1;
        tgt_s[s][k + 64] = (unsigned char)t2;
        __builtin_amdgcn_wave_barrier();
        const float* emrow = em + (size_t)b * NK_;
        float gold = emrow[k * K_ + t0] + emrow[(k + 32) * K_ + t1] + emrow[(k + 64) * K_ + t2];
        if (k > 0) gold += trans_s[(int)tgt_s[s][k - 1] * K_ + t0];
        gold += trans_s[(int)tgt_s[s][k + 31] * K_ + t1];
        gold += trans_s[(int)tgt_s[s][k + 63] * K_ + t2];

        float Ea = __expf(emb[0]);
        int   expo_sum = 0;
        float na = emb[K_];                   // prefetch t=1
        float* exs = &Eex[s][0];

        for (int t = 1; t <= 95; ++t) {
            const float cem = na;
            na = emb[(t + 1) * K_];           // t=95 reads split region: allocated, unused
            exs[k] = Ea;
            __builtin_amdgcn_wave_barrier();
            float fa = 0.0f;
#pragma unroll
            for (int j = 0; j < 8; j++) {
                f32x4 q = *(const f32x4*)&exs[4 * j];
                fa = fmaf(q[0], Ea2[4 * j],     fa);
                fa = fmaf(q[1], Ea2[4 * j + 1], fa);
                fa = fmaf(q[2], Ea2[4 * j + 2], fa);
                fa = fmaf(q[3], Ea2[4 * j + 3], fa);
            }
            Ea = fa * __expf(cem - 4.0f);
            __builtin_amdgcn_wave_barrier();

            if ((t % 12) == 0) {              // exact pow2 renorm; growth<=4.33^12 safe
                float m = Ea;
#pragma unroll
                for (int d = 16; d >= 1; d >>= 1) m = fmaxf(m, __shfl_xor(m, d));
                const unsigned int ebits = (__float_as_uint(m) >> 23) & 255u;
                const float sc = __uint_as_float((254u - ebits) << 23);
                Ea *= sc;
                expo_sum += (int)ebits - 127;
            }
        }

        float S = Ea;
#pragma unroll
        for (int d = 16; d >= 1; d >>= 1) S += __shfl_xor(S, d);
        const float logZ = __logf(S) + 380.0f + (float)expo_sum * 0.69314718055994531f;

        float gs = gold;
#pragma unroll
        for (int d = 16; d >= 1; d >>= 1) gs += __shfl_xor(gs, d);

        if (k == 0) ll[b] = gs - logZ;

    } else {
        // ================== VITERBI (tags) ==================
        float tca[K_];
#pragma unroll
        for (int p = 0; p < K_; p++) tca[p] = trans_s[p * K_ + k];

        float va = emb[0];
        float na = emb[K_];                   // prefetch t=1
        unsigned int bpw = 0;
        float* vxs = &vex[s][0];
        unsigned int* bps = &bp5[s][0];

        for (int it = 0; it < 7; ++it) {      // t = 1..84
            const int tb = it * 12 + 1;
            const int wi = it * 2;
            VSTEP(tb + 0, 0, wi)  VSTEP(tb + 1, 1, wi)  VSTEP(tb + 2, 2, wi)
            VSTEP(tb + 3, 3, wi)  VSTEP(tb + 4, 4, wi)  VSTEP(tb + 5, 5, wi)
            VSTEP(tb + 6, 0, wi + 1)  VSTEP(tb + 7, 1, wi + 1)  VSTEP(tb + 8, 2, wi + 1)
            VSTEP(tb + 9, 3, wi + 1)  VSTEP(tb + 10, 4, wi + 1) VSTEP(tb + 11, 5, wi + 1)
        }
        VSTEP(85, 0, 14) VSTEP(86, 1, 14) VSTEP(87, 2, 14)
        VSTEP(88, 3, 14) VSTEP(89, 4, 14) VSTEP(90, 5, 14)
        VSTEP(91, 0, 15) VSTEP(92, 1, 15) VSTEP(93, 2, 15)
        VSTEP(94, 3, 15) VSTEP(95, 4, 15)
        bps[k * 17 + 15] = bpw;               // partial word 15 (slots 0..4)
        __builtin_amdgcn_wave_barrier();

        // final argmax over 32 lanes (first-index tie-break)
        float bv = va; int bi = k;
#pragma unroll
        for (int d = 16; d >= 1; d >>= 1) {
            float ov = __shfl_xor(bv, d);
            int   oi = __shfl_xor(bi, d);
            if (ov > bv || (ov == bv && oi < bi)) { bv = ov; bi = oi; }
        }

        if (k == 0) {
            float* ot = out_tags + (size_t)b * T_;
            int tag = bi;
            ot[T_ - 1] = (float)tag;
            for (int t = T_ - 2; t >= 0; t--) {
                unsigned int wd = bps[tag * 17 + t / 6];
                tag = (int)((wd >> (5 * (t % 6))) & 31u);
                ot[t] = (float)tag;
            }
        }
    }
}

// ---------------------------------------------------------------------------
extern "C" void kernel_launch(void* const* d_in, const int* in_sizes, int n_in,
                              void* d_out, int out_size, void* d_ws, size_t ws_size,
                              hipStream_t stream)
{
    const float* hidden = (const float*)d_in[0];
    const int*   target = (const int*)d_in[1];
    const float* W      = (const float*)d_in[2];
    const float* bias   = (const float*)d_in[3];
    const float* trans  = (const float*)d_in[4];

    float* out      = (float*)d_out;
    float* out_tags = out;                    // B_*T_ tags (as f32)
    float* out_ll   = out + (size_t)B_ * T_;  // B_ log-likelihoods

    char* ws = (char*)d_ws;
    const size_t emB = (size_t)B_ * NK_ * 4;   // 100.66 MB
    const size_t ahB = (size_t)B_ * H_ * 2;    // 12.58 MB
    const size_t whB = (size_t)H_ * NK_ * 2;   // 4.72 MB

    float*    em  = (float*)ws;
    _Float16* Ath = (_Float16*)(ws + emB);
    _Float16* Atl = (_Float16*)(ws + emB + ahB);
    _Float16* Wth = (_Float16*)(ws + emB + 2 * ahB);
    _Float16* Wtl = (_Float16*)(ws + emB + 2 * ahB + whB);

    split_fused_kernel<<<(B_ * 96 + NK_ * 96) / 256, 256, 0, stream>>>(
        hidden, W, Ath, Atl, Wth, Wtl);

    gemm_mfma_sigmoid_kernel<<<1536, 256, 0, stream>>>(Ath, Atl, Wth, Wtl, bias, em);

    crf_roles_kernel<<<B_ / 4, 256, 0, stream>>>(em, target, trans, out_tags, out_ll);
}